// Round 5
// baseline (2563.342 us; speedup 1.0000x reference)
//
#include <hip/hip_runtime.h>

typedef __attribute__((ext_vector_type(8))) short bf16x8;
typedef __attribute__((ext_vector_type(4))) float f32x4;

#define L_DIM 24
#define B_DIM 32
#define S_DIM 512
#define H_DIM 1024
#define M_DIM 16384      // B*S
#define K_DIM 24576      // L*H
#define BSH  16777216    // B*S*H (fp32 elems per layer)
#define N_REAL 900
#define NP 1024          // padded N

// round-to-nearest-even fp32 -> bf16 (bit math, used in prep kernels)
__device__ __forceinline__ short f2bf(float f) {
  unsigned u = __builtin_bit_cast(unsigned, f);
  u += 0x7FFFu + ((u >> 16) & 1u);
  return (short)(u >> 16);
}

// packed fp32x2 -> bf16x2 (RNE), hardware cvt
__device__ __forceinline__ unsigned cvtpk(float lo, float hi) {
  unsigned r;
  asm volatile("v_cvt_pk_bf16_f32 %0, %1, %2" : "=v"(r) : "v"(lo), "v"(hi));
  return r;
}

// ---- P1: W1 [K][900] -> W1T bf16 [1024][K], zero-padded rows, swizzled (by n&7)
__global__ __launch_bounds__(256)
void prep_w1t_kernel(const float* __restrict__ w1, unsigned short* __restrict__ w1t) {
  __shared__ unsigned short t[64][72];
  const int n0 = blockIdx.x * 64;
  const int k0 = blockIdx.y * 64;
  const int tid = threadIdx.x;
  {
    const int nl = tid & 63;
    const int n = n0 + nl;
#pragma unroll
    for (int p = 0; p < 16; ++p) {
      const int kl = p * 4 + (tid >> 6);
      float v = (n < N_REAL) ? w1[(size_t)(k0 + kl) * N_REAL + n] : 0.f;
      t[nl][kl] = (unsigned short)f2bf(v);
    }
  }
  __syncthreads();
  {
    const int kl = tid & 63;
#pragma unroll
    for (int p = 0; p < 16; ++p) {
      const int nl2 = p * 4 + (tid >> 6);
      const int n = n0 + nl2;
      const int slot = ((kl >> 3) ^ (n & 7)) & 7;
      w1t[(size_t)n * K_DIM + k0 + slot * 8 + (kl & 7)] = t[nl2][kl];
    }
  }
}

// ---- P2: W2T fp32 [40][1024] (transposed, padded) + b1 padded [1024]
__global__ __launch_bounds__(256)
void prep_small_kernel(const float* __restrict__ w2, const float* __restrict__ b1,
                       float* __restrict__ w2t, float* __restrict__ b1p) {
  const int i = blockIdx.x * 256 + threadIdx.x;
  if (i < 40 * NP) {
    const int j = i >> 10, k = i & (NP - 1);
    w2t[i] = (k < N_REAL) ? w2[(size_t)k * 40 + j] : 0.f;
  }
  const int t2 = i - 40 * NP;
  if (t2 >= 0 && t2 < NP)
    b1p[t2] = (t2 < N_REAL) ? b1[t2] : 0.f;
}

// ---- G1: h1 = relu(x @ W1 + b1); A staged fp32->bf16 in-kernel (reg-staged),
//          B staged via global_load_lds from pre-swizzled W1T. 256x256, 4-phase.
#define SBAR() do { __builtin_amdgcn_sched_barrier(0); __builtin_amdgcn_s_barrier(); __builtin_amdgcn_sched_barrier(0); } while (0)
#define WAIT_LGKM0() do { asm volatile("s_waitcnt lgkmcnt(0)" ::: "memory"); __builtin_amdgcn_sched_barrier(0); } while (0)
#define VMWAIT(N) do { asm volatile("s_waitcnt vmcnt(" #N ")" ::: "memory"); __builtin_amdgcn_sched_barrier(0); } while (0)

// stage one 128-row half of the B tile (16 KiB): 2 x global_load_lds per thread
#define STAGE_B(DSTREG, HALF, TK) do {                                                 \
  _Pragma("unroll")                                                                    \
  for (int _i = 0; _i < 2; ++_i) {                                                     \
    const int _ch = wid * 2 + _i;                                                      \
    const int _row = (HALF) * 128 + _ch * 8 + (lane >> 3);                             \
    __builtin_amdgcn_global_load_lds(                                                  \
      (const __attribute__((address_space(1))) void*)(w1t +                            \
          (size_t)(n0 + _row) * K_DIM + (TK) * 64 + (lane & 7) * 8),                   \
      (__attribute__((address_space(3))) void*)((DSTREG) + (HALF) * 16384 + _ch * 1024), \
      16, 0, 0);                                                                       \
  }                                                                                    \
} while (0)

// issue the 4 fp32 global loads for one 128-row A half-tile (16 floats/thread)
#define A_LOAD(REGS, TK, H) do {                                                       \
  const float* _p = hs + (size_t)((TK) >> 4) * BSH +                                   \
      (size_t)(m0 + (H) * 128 + ar_row) * 1024 + (((TK) & 15) * 64 + ar_kof);          \
  REGS[0] = *(const float4*)_p;                                                        \
  REGS[1] = *(const float4*)(_p + 4);                                                  \
  REGS[2] = *(const float4*)(_p + 8);                                                  \
  REGS[3] = *(const float4*)(_p + 12);                                                 \
} while (0)

// convert 16 fp32 -> 16 bf16, write 2 swizzled ds_write_b128
#define A_CVT_WRITE(REGS, DST, H) do {                                                 \
  uint4 _q0, _q1;                                                                      \
  _q0.x = cvtpk(REGS[0].x, REGS[0].y); _q0.y = cvtpk(REGS[0].z, REGS[0].w);            \
  _q0.z = cvtpk(REGS[1].x, REGS[1].y); _q0.w = cvtpk(REGS[1].z, REGS[1].w);            \
  _q1.x = cvtpk(REGS[2].x, REGS[2].y); _q1.y = cvtpk(REGS[2].z, REGS[2].w);            \
  _q1.z = cvtpk(REGS[3].x, REGS[3].y); _q1.w = cvtpk(REGS[3].z, REGS[3].w);            \
  const int _r = (H) * 128 + ar_row;                                                   \
  const int _g0 = (tid & 3) * 2;                                                       \
  *(uint4*)((DST) + _r * 128 + ((_g0 ^ (_r & 7)) * 16)) = _q0;                         \
  *(uint4*)((DST) + _r * 128 + (((_g0 + 1) ^ (_r & 7)) * 16)) = _q1;                   \
} while (0)

#define LDA4(AV, MIBASE, ABUF) do {                                                    \
  _Pragma("unroll")                                                                    \
  for (int _mi = 0; _mi < 4; ++_mi) {                                                  \
    _Pragma("unroll")                                                                  \
    for (int _kk = 0; _kk < 2; ++_kk) {                                                \
      const int _r = wr * 128 + ((MIBASE) + _mi) * 16 + r15;                           \
      AV[_mi][_kk] = *(const bf16x8*)((ABUF) + _r * 128 + (((_kk)*4 + hi4) ^ (_r & 7)) * 16); \
    }                                                                                  \
  }                                                                                    \
} while (0)

#define LDB2(BV, NIBASE, BBUF) do {                                                    \
  _Pragma("unroll")                                                                    \
  for (int _ni = 0; _ni < 2; ++_ni) {                                                  \
    _Pragma("unroll")                                                                  \
    for (int _kk = 0; _kk < 2; ++_kk) {                                                \
      const int _r = wc * 64 + ((NIBASE) + _ni) * 16 + r15;                            \
      BV[_ni][_kk] = *(const bf16x8*)((BBUF) + _r * 128 + (((_kk)*4 + hi4) ^ (_r & 7)) * 16); \
    }                                                                                  \
  }                                                                                    \
} while (0)

#define MFMA_Q(AV, BV, MIBASE, NIBASE) do {                                            \
  _Pragma("unroll")                                                                    \
  for (int _mi = 0; _mi < 4; ++_mi)                                                    \
    _Pragma("unroll")                                                                  \
    for (int _ni = 0; _ni < 2; ++_ni)                                                  \
      _Pragma("unroll")                                                                \
      for (int _kk = 0; _kk < 2; ++_kk)                                                \
        acc[(MIBASE) + _mi][(NIBASE) + _ni] = __builtin_amdgcn_mfma_f32_16x16x32_bf16( \
            AV[_mi][_kk], BV[_ni][_kk], acc[(MIBASE) + _mi][(NIBASE) + _ni], 0, 0, 0); \
} while (0)

// one K-tile = 4 phases. SA: stage A(t+1) (loads ph1/ph2, cvt+write ph3/ph4 behind
// counted vmcnt). SB: stage B(t+2) via gload_lds at ph3/ph4.
#define TILE_F(T, ABUF, BBUF, ABUFN, SA, SB, W3STMT, W4STMT) do {                      \
  /* ---- phase 1 ---- */                                                              \
  if (SA) A_LOAD(ar0, (T) + 1, 0);                                                     \
  LDA4(av, 0, (ABUF));                                                                 \
  LDB2(bv0, 0, (BBUF));                                                                \
  SBAR();                                                                              \
  WAIT_LGKM0();                                                                        \
  __builtin_amdgcn_s_setprio(1);                                                       \
  MFMA_Q(av, bv0, 0, 0);                                                               \
  __builtin_amdgcn_s_setprio(0);                                                       \
  SBAR();                                                                              \
  /* ---- phase 2 ---- */                                                              \
  if (SA) A_LOAD(ar1, (T) + 1, 1);                                                     \
  LDB2(bv1, 2, (BBUF));                                                                \
  SBAR();                                                                              \
  WAIT_LGKM0();                                                                        \
  __builtin_amdgcn_s_setprio(1);                                                       \
  MFMA_Q(av, bv1, 0, 2);                                                               \
  __builtin_amdgcn_s_setprio(0);                                                       \
  SBAR();                                                                              \
  /* ---- phase 3 ---- */                                                              \
  if (SA) { W3STMT; A_CVT_WRITE(ar0, (ABUFN), 0); }                                    \
  if (SB) STAGE_B((BBUF), 0, (T) + 2);                                                 \
  LDA4(av, 4, (ABUF));                                                                 \
  SBAR();                                                                              \
  WAIT_LGKM0();                                                                        \
  __builtin_amdgcn_s_setprio(1);                                                       \
  MFMA_Q(av, bv1, 4, 2);                                                               \
  __builtin_amdgcn_s_setprio(0);                                                       \
  SBAR();                                                                              \
  /* ---- phase 4 ---- */                                                              \
  if (SA) { W4STMT; A_CVT_WRITE(ar1, (ABUFN), 1); }                                    \
  if (SB) STAGE_B((BBUF), 1, (T) + 2);                                                 \
  SBAR();                                                                              \
  WAIT_LGKM0();                                                                        \
  __builtin_amdgcn_s_setprio(1);                                                       \
  MFMA_Q(av, bv0, 4, 0);                                                               \
  __builtin_amdgcn_s_setprio(0);                                                       \
  SBAR();                                                                              \
} while (0)

__global__ __launch_bounds__(512, 2)
void gemm1_fused_kernel(const float* __restrict__ hs,
                        const unsigned short* __restrict__ w1t,
                        const float* __restrict__ b1p,
                        float* __restrict__ h1) {
  extern __shared__ char L[];   // 128 KiB: A0|B0|A1|B1, 32 KiB each
  char* const A0 = L;
  char* const B0 = L + 32768;
  char* const A1 = L + 65536;
  char* const B1 = L + 65536 + 32768;

  const int tid = threadIdx.x;
  const int lane = tid & 63;
  const int wid = tid >> 6;          // 0..7
  const int wr = wid >> 2;           // 0..1 (128-row band)
  const int wc = wid & 3;            // 0..3 (64-col band)
  const int r15 = lane & 15;
  const int hi4 = lane >> 4;         // 0..3

  // A reg-staging geometry: 4 threads per row, 16 consecutive k each
  const int ar_row = tid >> 2;       // 0..127 within half
  const int ar_kof = (tid & 3) * 16;

  // bijective XCD mapping: xcd = hw&7 owns m-panels [xcd*8, xcd*8+8) x 4 n-blocks
  const int hw = blockIdx.x;
  const int mb = (hw & 7) * 8 + (hw >> 5);
  const int nb = (hw >> 3) & 3;
  const int m0 = mb * 256;
  const int n0 = nb * 256;

  f32x4 acc[8][4] = {};
  bf16x8 av[4][2], bv0[2][2], bv1[2][2];
  float4 ar0[4], ar1[4];

  // prologue: A0 fp32 loads (8), B0 (4), B1 (4); counted drains; cvt+write A0
  A_LOAD(ar0, 0, 0);
  A_LOAD(ar1, 0, 1);
  STAGE_B(B0, 0, 0);
  STAGE_B(B0, 1, 0);
  STAGE_B(B1, 0, 1);
  STAGE_B(B1, 1, 1);
  VMWAIT(12);
  A_CVT_WRITE(ar0, A0, 0);
  VMWAIT(8);
  A_CVT_WRITE(ar1, A0, 1);
  VMWAIT(4);            // B0 landed; B1 (4) stays in flight
  WAIT_LGKM0();
  SBAR();

  for (int kt = 0; kt < 191; ++kt) {
    TILE_F(2 * kt,     A0, B0, A1, 1, 1, VMWAIT(4), VMWAIT(2));
    TILE_F(2 * kt + 1, A1, B1, A0, 1, 1, VMWAIT(4), VMWAIT(2));
  }
  // tail: tile 382 stages A383 only (vmcnt(0) at ph4); tile 383 computes only
  TILE_F(382, A0, B0, A1, 1, 0, VMWAIT(4), VMWAIT(0));
  TILE_F(383, A1, B1, A0, 0, 0, (void)0, (void)0);

  // epilogue: relu(acc + b1); C/D: col = lane&15, row = (lane>>4)*4 + r
#pragma unroll
  for (int mi = 0; mi < 8; ++mi) {
#pragma unroll
    for (int ni = 0; ni < 4; ++ni) {
      const int n = n0 + wc * 64 + ni * 16 + r15;
      const float bias = b1p[n];
#pragma unroll
      for (int r = 0; r < 4; ++r) {
        const int m = m0 + wr * 128 + mi * 16 + hi4 * 4 + r;
        const float v = acc[mi][ni][r] + bias;
        h1[(size_t)m * NP + n] = v > 0.f ? v : 0.f;
      }
    }
  }
}

// ---- K2: logits = sigmoid(relu(h1 @ W2 + b2) @ W3 + b3), one wave/row (stride NP)
__global__ __launch_bounds__(256)
void layer23_kernel(const float* __restrict__ h1, const float* __restrict__ w2t,
                    const float* __restrict__ b2, const float* __restrict__ w3,
                    const float* __restrict__ b3, float* __restrict__ logits) {
  const int wave = (blockIdx.x * 256 + threadIdx.x) >> 6;
  const int lane = threadIdx.x & 63;
  const float* hrow = h1 + (size_t)wave * NP;
  float acc = 0.f;
  if (lane < 40) {
    const float* wrow = w2t + lane * NP;
    for (int k = 0; k < NP; k += 8) {
      float4 h0 = *(const float4*)(hrow + k);
      float4 h4 = *(const float4*)(hrow + k + 4);
      float4 w0 = *(const float4*)(wrow + k);
      float4 w4 = *(const float4*)(wrow + k + 4);
      acc += h0.x * w0.x + h0.y * w0.y + h0.z * w0.z + h0.w * w0.w;
      acc += h4.x * w4.x + h4.y * w4.y + h4.z * w4.z + h4.w * w4.w;
    }
    acc += b2[lane];
    acc = acc > 0.f ? acc : 0.f;
    acc *= w3[lane];
  }
#pragma unroll
  for (int off = 32; off > 0; off >>= 1)
    acc += __shfl_down(acc, off);
  if (lane == 0)
    logits[wave] = 1.f / (1.f + expf(-(acc + b3[0])));
}

// ---- K3: ragged gather
__global__ __launch_bounds__(256)
void gather_kernel(const int* __restrict__ starts, const float* __restrict__ logits,
                   float* __restrict__ out) {
  const int i = blockIdx.x * 256 + threadIdx.x;
  if (i >= M_DIM) return;
  const int st = starts[i];
  int idx = st;
  if (idx < 0) idx = 0;
  if (idx > S_DIM - 1) idx = S_DIM - 1;
  out[i] = (st != 0) ? logits[((i >> 9) << 9) + idx] : 0.f;
}

extern "C" void kernel_launch(void* const* d_in, const int* in_sizes, int n_in,
                              void* d_out, int out_size, void* d_ws, size_t ws_size,
                              hipStream_t stream) {
  const float* hs = (const float*)d_in[0];
  const float* W1 = (const float*)d_in[1];
  const float* b1 = (const float*)d_in[2];
  const float* W2 = (const float*)d_in[3];
  const float* b2 = (const float*)d_in[4];
  const float* W3 = (const float*)d_in[5];
  const float* b3 = (const float*)d_in[6];
  const int* starts = (const int*)d_in[7];
  float* out = (float*)d_out;
  char* ws = (char*)d_ws;

  const size_t W1T_BYTES = (size_t)NP * K_DIM * 2;            //  50,331,648
  const size_t H1_BYTES  = (size_t)M_DIM * NP * 4;            //  67,108,864
  const size_t W2T_BYTES = 40 * NP * 4;
  const size_t B1P_BYTES = NP * 4;

  unsigned short* w1t = (unsigned short*)ws;
  float* h1           = (float*)(ws + W1T_BYTES);
  float* w2t          = (float*)(ws + W1T_BYTES + H1_BYTES);
  float* b1p          = (float*)(ws + W1T_BYTES + H1_BYTES + W2T_BYTES);
  float* logits       = (float*)(ws + W1T_BYTES + H1_BYTES + W2T_BYTES + B1P_BYTES);

  hipFuncSetAttribute((const void*)gemm1_fused_kernel,
                      hipFuncAttributeMaxDynamicSharedMemorySize, 131072);

  prep_w1t_kernel<<<dim3(16, 384), 256, 0, stream>>>(W1, w1t);
  prep_small_kernel<<<164, 256, 0, stream>>>(W2, b1, w2t, b1p);
  gemm1_fused_kernel<<<256, 512, 131072, stream>>>(hs, w1t, b1p, h1);
  layer23_kernel<<<4096, 256, 0, stream>>>(h1, w2t, b2, W3, b3, logits);
  gather_kernel<<<64, 256, 0, stream>>>(starts, logits, out);
}

// Round 6
// 2099.041 us; speedup vs baseline: 1.2212x; 1.2212x over previous
//
#include <hip/hip_runtime.h>

typedef __attribute__((ext_vector_type(8))) short bf16x8;
typedef __attribute__((ext_vector_type(4))) float f32x4;

#define L_DIM 24
#define B_DIM 32
#define S_DIM 512
#define H_DIM 1024
#define M_DIM 16384      // B*S
#define K_DIM 24576      // L*H
#define BSH  16777216    // B*S*H (fp32 elems per layer)
#define N_REAL 900
#define NP 1024          // padded N

// round-to-nearest-even fp32 -> bf16 (bit math, prep kernels)
__device__ __forceinline__ short f2bf(float f) {
  unsigned u = __builtin_bit_cast(unsigned, f);
  u += 0x7FFFu + ((u >> 16) & 1u);
  return (short)(u >> 16);
}

// packed fp32x2 -> bf16x2 (RNE), hardware cvt
__device__ __forceinline__ unsigned cvtpk(float lo, float hi) {
  unsigned r;
  asm volatile("v_cvt_pk_bf16_f32 %0, %1, %2" : "=v"(r) : "v"(lo), "v"(hi));
  return r;
}

// ---- P1: W1 [K][900] -> W1T bf16 [1024][K], zero-padded rows, swizzled (by n&7)
__global__ __launch_bounds__(256)
void prep_w1t_kernel(const float* __restrict__ w1, unsigned short* __restrict__ w1t) {
  __shared__ unsigned short t[64][72];
  const int n0 = blockIdx.x * 64;
  const int k0 = blockIdx.y * 64;
  const int tid = threadIdx.x;
  {
    const int nl = tid & 63;
    const int n = n0 + nl;
#pragma unroll
    for (int p = 0; p < 16; ++p) {
      const int kl = p * 4 + (tid >> 6);
      float v = (n < N_REAL) ? w1[(size_t)(k0 + kl) * N_REAL + n] : 0.f;
      t[nl][kl] = (unsigned short)f2bf(v);
    }
  }
  __syncthreads();
  {
    const int kl = tid & 63;
#pragma unroll
    for (int p = 0; p < 16; ++p) {
      const int nl2 = p * 4 + (tid >> 6);
      const int n = n0 + nl2;
      const int slot = ((kl >> 3) ^ (n & 7)) & 7;
      w1t[(size_t)n * K_DIM + k0 + slot * 8 + (kl & 7)] = t[nl2][kl];
    }
  }
}

// ---- P2: W2T fp32 [40][1024] (transposed, padded) + b1 padded [1024]
__global__ __launch_bounds__(256)
void prep_small_kernel(const float* __restrict__ w2, const float* __restrict__ b1,
                       float* __restrict__ w2t, float* __restrict__ b1p) {
  const int i = blockIdx.x * 256 + threadIdx.x;
  if (i < 40 * NP) {
    const int j = i >> 10, k = i & (NP - 1);
    w2t[i] = (k < N_REAL) ? w2[(size_t)k * 40 + j] : 0.f;
  }
  const int t2 = i - 40 * NP;
  if (t2 >= 0 && t2 < NP)
    b1p[t2] = (t2 < N_REAL) ? b1[t2] : 0.f;
}

// =====================================================================
// G1: h1 = relu(x @ W1 + b1). 256x256 tile, BK=64, 4-phase kk-split,
// A fused fp32->bf16 (coalesced reg-stage, depth t+2), B via gload_lds.
// =====================================================================
#define SBAR() do { __builtin_amdgcn_sched_barrier(0); __builtin_amdgcn_s_barrier(); __builtin_amdgcn_sched_barrier(0); } while (0)
#define WAIT_LGKM0() do { asm volatile("s_waitcnt lgkmcnt(0)" ::: "memory"); __builtin_amdgcn_sched_barrier(0); } while (0)
#define VMWAIT(N) do { asm volatile("s_waitcnt vmcnt(" #N ")" ::: "memory"); __builtin_amdgcn_sched_barrier(0); } while (0)

// stage one 128-row half of the B tile (16 KiB): 2 gload_lds per thread
#define STAGE_B(DSTREG, HALF, TK) do {                                                 \
  _Pragma("unroll")                                                                    \
  for (int _i = 0; _i < 2; ++_i) {                                                     \
    const int _ch = wid * 2 + _i;                                                      \
    const int _row = (HALF) * 128 + _ch * 8 + (lane >> 3);                             \
    __builtin_amdgcn_global_load_lds(                                                  \
      (const __attribute__((address_space(1))) void*)(w1t +                            \
          (size_t)(n0 + _row) * K_DIM + (TK) * 64 + (lane & 7) * 8),                   \
      (__attribute__((address_space(3))) void*)((DSTREG) + (HALF) * 16384 + _ch * 1024), \
      16, 0, 0);                                                                       \
  }                                                                                    \
} while (0)

// coalesced A half-tile loads: 4 x float4, each instr = 4 rows x 256B = 1KB contiguous
#define A_LOADH(REGS, TK, H) do {                                                      \
  const float* _p = hs + (size_t)((TK) >> 4) * BSH +                                   \
      (size_t)(m0 + (H) * 128 + wid * 16 + (lane >> 4)) * 1024 +                       \
      (((TK) & 15) * 64 + (lane & 15) * 4);                                            \
  REGS[0] = *(const float4*)_p;                                                        \
  REGS[1] = *(const float4*)(_p + 4 * 1024);                                           \
  REGS[2] = *(const float4*)(_p + 8 * 1024);                                           \
  REGS[3] = *(const float4*)(_p + 12 * 1024);                                         \
} while (0)

// cvt 16 fp32 -> 16 bf16, 4 swizzled ds_write_b64 (even bank distribution)
#define A_CVT_WRITEH(REGS, DST, H) do {                                                \
  _Pragma("unroll")                                                                    \
  for (int _j = 0; _j < 4; ++_j) {                                                     \
    uint2 _v;                                                                          \
    _v.x = cvtpk(REGS[_j].x, REGS[_j].y);                                              \
    _v.y = cvtpk(REGS[_j].z, REGS[_j].w);                                              \
    const int _r = (H) * 128 + wid * 16 + _j * 4 + (lane >> 4);                        \
    const int _c = lane & 15;                                                          \
    const int _b = _r * 128 + ((((_c >> 1) ^ (_r & 7)) << 4) + (_c & 1) * 8);          \
    *(uint2*)((DST) + _b) = _v;                                                        \
  }                                                                                    \
} while (0)

#define LD_A(AV, MIBASE, KK, ABUF) do {                                                \
  _Pragma("unroll")                                                                    \
  for (int _mi = 0; _mi < 4; ++_mi) {                                                  \
    const int _r = wr * 128 + ((MIBASE) + _mi) * 16 + r15;                             \
    AV[_mi] = *(const bf16x8*)((ABUF) + _r * 128 + ((((KK) * 4 + hi4) ^ (_r & 7)) * 16)); \
  }                                                                                    \
} while (0)

#define LD_B(BV, KK, BBUF) do {                                                        \
  _Pragma("unroll")                                                                    \
  for (int _ni = 0; _ni < 4; ++_ni) {                                                  \
    const int _r = wc * 64 + _ni * 16 + r15;                                           \
    BV[_ni] = *(const bf16x8*)((BBUF) + _r * 128 + ((((KK) * 4 + hi4) ^ (_r & 7)) * 16)); \
  }                                                                                    \
} while (0)

#define MFMA_H(AV, BV, MIBASE) do {                                                    \
  _Pragma("unroll")                                                                    \
  for (int _mi = 0; _mi < 4; ++_mi)                                                    \
    _Pragma("unroll")                                                                  \
    for (int _ni = 0; _ni < 4; ++_ni)                                                  \
      acc[(MIBASE) + _mi][_ni] = __builtin_amdgcn_mfma_f32_16x16x32_bf16(              \
          AV[_mi], BV[_ni], acc[(MIBASE) + _mi][_ni], 0, 0, 0);                        \
} while (0)

// one K-tile = 4 phases (kk-split). ARLD: regs for A(T+2) loads (ph1/ph2).
// ARCV: regs holding A(T+1), cvt+written to ABN (ph3/ph4). B(T+2) staged ph4.
#define TILE_F(T, AB, BB, ABN, ARLD, ARCV, SA, SC, SB, W3STMT, W4STMT) do {            \
  /* phase 1: kk0, mi0-3 */                                                            \
  if (SA) A_LOADH(ARLD##0, (T) + 2, 0);                                                \
  LD_A(av0, 0, 0, (AB));                                                               \
  LD_B(bv, 0, (BB));                                                                   \
  SBAR();                                                                              \
  WAIT_LGKM0();                                                                        \
  __builtin_amdgcn_s_setprio(1);                                                       \
  MFMA_H(av0, bv, 0);                                                                  \
  __builtin_amdgcn_s_setprio(0);                                                       \
  SBAR();                                                                              \
  /* phase 2: kk0, mi4-7 */                                                            \
  if (SA) A_LOADH(ARLD##1, (T) + 2, 1);                                                \
  LD_A(av1, 4, 0, (AB));                                                               \
  SBAR();                                                                              \
  WAIT_LGKM0();                                                                        \
  __builtin_amdgcn_s_setprio(1);                                                       \
  MFMA_H(av1, bv, 4);                                                                  \
  __builtin_amdgcn_s_setprio(0);                                                       \
  SBAR();                                                                              \
  /* phase 3: kk1, mi0-3 ; cvt+write A(T+1) h0 */                                      \
  W3STMT;                                                                              \
  if (SC) A_CVT_WRITEH(ARCV##0, (ABN), 0);                                             \
  LD_A(av0, 0, 1, (AB));                                                               \
  LD_B(bv, 1, (BB));                                                                   \
  SBAR();                                                                              \
  WAIT_LGKM0();                                                                        \
  __builtin_amdgcn_s_setprio(1);                                                       \
  MFMA_H(av0, bv, 0);                                                                  \
  __builtin_amdgcn_s_setprio(0);                                                       \
  SBAR();                                                                              \
  /* phase 4: kk1, mi4-7 ; cvt+write A(T+1) h1 ; stage B(T+2) */                       \
  W4STMT;                                                                              \
  if (SC) A_CVT_WRITEH(ARCV##1, (ABN), 1);                                             \
  if (SB) { STAGE_B((BB), 0, (T) + 2); STAGE_B((BB), 1, (T) + 2); }                    \
  LD_A(av1, 4, 1, (AB));                                                               \
  SBAR();                                                                              \
  WAIT_LGKM0();                                                                        \
  __builtin_amdgcn_s_setprio(1);                                                       \
  MFMA_H(av1, bv, 4);                                                                  \
  __builtin_amdgcn_s_setprio(0);                                                       \
  SBAR();                                                                              \
} while (0)

__global__ __launch_bounds__(512, 2)
void gemm1_fused2_kernel(const float* __restrict__ hs,
                         const unsigned short* __restrict__ w1t,
                         const float* __restrict__ b1p,
                         float* __restrict__ h1) {
  extern __shared__ char L[];   // 128 KiB: A0|B0|A1|B1, 32 KiB each
  char* const Ab0 = L;
  char* const Bb0 = L + 32768;
  char* const Ab1 = L + 65536;
  char* const Bb1 = L + 65536 + 32768;

  const int tid = threadIdx.x;
  const int lane = tid & 63;
  const int wid = tid >> 6;          // 0..7
  const int wr = wid >> 2;           // 0..1 (128-row band)
  const int wc = wid & 3;            // 0..3 (64-col band)
  const int r15 = lane & 15;
  const int hi4 = lane >> 4;         // 0..3

  // bijective XCD mapping: xcd = hw&7 owns m-panels [xcd*8, xcd*8+8) x 4 n-blocks
  const int hw = blockIdx.x;
  const int mb = (hw & 7) * 8 + (hw >> 5);
  const int nb = (hw >> 3) & 3;
  const int m0 = mb * 256;
  const int n0 = nb * 256;

  f32x4 acc[8][4] = {};
  bf16x8 av0[4], av1[4], bv[4];
  float4 ar_e0[4], ar_e1[4], ar_o0[4], ar_o1[4];

  // ---- prologue ----
  A_LOADH(ar_e0, 0, 0);            // A(0) h0  (4)
  A_LOADH(ar_e1, 0, 1);            // A(0) h1  (4)
  STAGE_B(Bb0, 0, 0);              // B(0)     (2)
  STAGE_B(Bb0, 1, 0);              //          (2)  -> 12 outstanding
  VMWAIT(4);                       // drain A(0)
  A_CVT_WRITEH(ar_e0, Ab0, 0);
  A_CVT_WRITEH(ar_e1, Ab0, 1);
  A_LOADH(ar_o0, 1, 0);            // A(1) h0  (4)
  A_LOADH(ar_o1, 1, 1);            // A(1) h1  (4)  -> [B0 4, A1 8]
  STAGE_B(Bb1, 0, 1);              // B(1)     (2)
  STAGE_B(Bb1, 1, 1);              //          (2)  -> 16
  VMWAIT(12);                      // drain B(0) -> E = [A1 8, B1 4] = 12
  WAIT_LGKM0();                    // own ds_writes drained
  SBAR();

  // ---- main loop: tiles 0..381 ----
  for (int kt = 0; kt < 191; ++kt) {
    const int t = 2 * kt;
    TILE_F(t,     Ab0, Bb0, Ab1, ar_e, ar_o, 1, 1, 1, VMWAIT(16), VMWAIT(8));
    TILE_F(t + 1, Ab1, Bb1, Ab0, ar_o, ar_e, 1, 1, 1, VMWAIT(16), VMWAIT(8));
  }
  // ---- tail: tile 382 (cvt A383, no new loads), tile 383 (compute only) ----
  TILE_F(382, Ab0, Bb0, Ab1, ar_e, ar_o, 0, 1, 0, VMWAIT(8), VMWAIT(0));
  TILE_F(383, Ab1, Bb1, Ab0, ar_o, ar_e, 0, 0, 0, (void)0, (void)0);

  // ---- epilogue: relu(acc + b1); C/D: col = lane&15, row = (lane>>4)*4 + r
#pragma unroll
  for (int mi = 0; mi < 8; ++mi) {
#pragma unroll
    for (int ni = 0; ni < 4; ++ni) {
      const int n = n0 + wc * 64 + ni * 16 + r15;
      const float bias = b1p[n];
#pragma unroll
      for (int r = 0; r < 4; ++r) {
        const int m = m0 + wr * 128 + mi * 16 + hi4 * 4 + r;
        const float v = acc[mi][ni][r] + bias;
        h1[(size_t)m * NP + n] = v > 0.f ? v : 0.f;
      }
    }
  }
}

// ---- K2: logits = sigmoid(relu(h1 @ W2 + b2) @ W3 + b3), one wave/row
__global__ __launch_bounds__(256)
void layer23_kernel(const float* __restrict__ h1, const float* __restrict__ w2t,
                    const float* __restrict__ b2, const float* __restrict__ w3,
                    const float* __restrict__ b3, float* __restrict__ logits) {
  const int wave = (blockIdx.x * 256 + threadIdx.x) >> 6;
  const int lane = threadIdx.x & 63;
  const float* hrow = h1 + (size_t)wave * NP;
  float acc = 0.f;
  if (lane < 40) {
    const float* wrow = w2t + lane * NP;
    for (int k = 0; k < NP; k += 8) {
      float4 h0 = *(const float4*)(hrow + k);
      float4 h4 = *(const float4*)(hrow + k + 4);
      float4 w0 = *(const float4*)(wrow + k);
      float4 w4 = *(const float4*)(wrow + k + 4);
      acc += h0.x * w0.x + h0.y * w0.y + h0.z * w0.z + h0.w * w0.w;
      acc += h4.x * w4.x + h4.y * w4.y + h4.z * w4.z + h4.w * w4.w;
    }
    acc += b2[lane];
    acc = acc > 0.f ? acc : 0.f;
    acc *= w3[lane];
  }
#pragma unroll
  for (int off = 32; off > 0; off >>= 1)
    acc += __shfl_down(acc, off);
  if (lane == 0)
    logits[wave] = 1.f / (1.f + expf(-(acc + b3[0])));
}

// ---- K3: ragged gather
__global__ __launch_bounds__(256)
void gather_kernel(const int* __restrict__ starts, const float* __restrict__ logits,
                   float* __restrict__ out) {
  const int i = blockIdx.x * 256 + threadIdx.x;
  if (i >= M_DIM) return;
  const int st = starts[i];
  int idx = st;
  if (idx < 0) idx = 0;
  if (idx > S_DIM - 1) idx = S_DIM - 1;
  out[i] = (st != 0) ? logits[((i >> 9) << 9) + idx] : 0.f;
}

extern "C" void kernel_launch(void* const* d_in, const int* in_sizes, int n_in,
                              void* d_out, int out_size, void* d_ws, size_t ws_size,
                              hipStream_t stream) {
  const float* hs = (const float*)d_in[0];
  const float* W1 = (const float*)d_in[1];
  const float* b1 = (const float*)d_in[2];
  const float* W2 = (const float*)d_in[3];
  const float* b2 = (const float*)d_in[4];
  const float* W3 = (const float*)d_in[5];
  const float* b3 = (const float*)d_in[6];
  const int* starts = (const int*)d_in[7];
  float* out = (float*)d_out;
  char* ws = (char*)d_ws;

  const size_t W1T_BYTES = (size_t)NP * K_DIM * 2;            //  50,331,648
  const size_t H1_BYTES  = (size_t)M_DIM * NP * 4;            //  67,108,864
  const size_t W2T_BYTES = 40 * NP * 4;
  const size_t B1P_BYTES = NP * 4;

  unsigned short* w1t = (unsigned short*)ws;
  float* h1           = (float*)(ws + W1T_BYTES);
  float* w2t          = (float*)(ws + W1T_BYTES + H1_BYTES);
  float* b1p          = (float*)(ws + W1T_BYTES + H1_BYTES + W2T_BYTES);
  float* logits       = (float*)(ws + W1T_BYTES + H1_BYTES + W2T_BYTES + B1P_BYTES);

  hipFuncSetAttribute((const void*)gemm1_fused2_kernel,
                      hipFuncAttributeMaxDynamicSharedMemorySize, 131072);

  prep_w1t_kernel<<<dim3(16, 384), 256, 0, stream>>>(W1, w1t);
  prep_small_kernel<<<164, 256, 0, stream>>>(W2, b1, w2t, b1p);
  gemm1_fused2_kernel<<<256, 512, 131072, stream>>>(hs, w1t, b1p, h1);
  layer23_kernel<<<4096, 256, 0, stream>>>(h1, w2t, b2, W3, b3, logits);
  gather_kernel<<<64, 256, 0, stream>>>(starts, logits, out);
}

// Round 8
// 1284.634 us; speedup vs baseline: 1.9954x; 1.6340x over previous
//
#include <hip/hip_runtime.h>

typedef __attribute__((ext_vector_type(8))) short bf16x8;
typedef __attribute__((ext_vector_type(4))) float f32x4;

#define L_DIM 24
#define B_DIM 32
#define S_DIM 512
#define H_DIM 1024
#define M_DIM 16384      // B*S
#define K_DIM 24576      // L*H
#define N_REAL 900
#define NP 1024          // padded N

// round-to-nearest-even fp32 -> bf16
__device__ __forceinline__ short f2bf(float f) {
  unsigned u = __builtin_bit_cast(unsigned, f);
  u += 0x7FFFu + ((u >> 16) & 1u);
  return (short)(u >> 16);
}

// does sorted srow[0..511] contain s? 10-step lower_bound (512 needs 10 halvings;
// 9 left a 2-wide window -> missed rows in R7). Extra iterations at convergence
// are no-ops: invariant guarantees srow[lo] >= s there.
__device__ __forceinline__ bool row_needed(const int* __restrict__ srow, int s) {
  int lo = 0, hi = 512;
#pragma unroll
  for (int it = 0; it < 10; ++it) {
    const int mid = (lo + hi) >> 1;
    const int v = (mid < 512) ? srow[mid] : 0x7fffffff;
    if (v < s) lo = mid + 1; else hi = mid;
  }
  return lo < 512 && srow[lo] == s;
}

// ---- P0: hidden_states fp32 [L][B][S][H] -> A bf16 [M][K], pre-swizzled:
// element (m,k) at k' = (k & ~63) + (((k>>3 & 7) ^ (m & 7)) * 8) + (k & 7).
// Rows never gathered are skipped (their stale contents are never read).
__global__ __launch_bounds__(256)
void conv_a_kernel(const float* __restrict__ hs, const int* __restrict__ starts,
                   unsigned short* __restrict__ a) {
  for (int m = blockIdx.x; m < M_DIM; m += gridDim.x) {
    const int b = m >> 9, s = m & 511;
    if (s == 0 || !row_needed(starts + b * 512, s)) continue;
    const int m7 = m & 7;
    unsigned short* dstRow = a + (size_t)m * K_DIM;
#pragma unroll
    for (int i = 0; i < 12; ++i) {
      const int g = threadIdx.x + i * 256;        // granule (8 elems)
      const int l = g >> 7;
      const int h = (g & 127) * 8;
      const float* src = hs + (((size_t)l * B_DIM + b) * S_DIM + s) * H_DIM + h;
      float4 f0 = *(const float4*)src;
      float4 f1 = *(const float4*)(src + 4);
      bf16x8 p;
      p[0] = f2bf(f0.x); p[1] = f2bf(f0.y); p[2] = f2bf(f0.z); p[3] = f2bf(f0.w);
      p[4] = f2bf(f1.x); p[5] = f2bf(f1.y); p[6] = f2bf(f1.z); p[7] = f2bf(f1.w);
      const int slot = (g & 7) ^ m7;
      *(bf16x8*)(dstRow + (g & ~7) * 8 + slot * 8) = p;
    }
  }
}

// ---- P1: W1 [K][900] -> W1T bf16 [1024][K], zero-padded rows, swizzled (by n&7)
__global__ __launch_bounds__(256)
void prep_w1t_kernel(const float* __restrict__ w1, unsigned short* __restrict__ w1t) {
  __shared__ unsigned short t[64][72];
  const int n0 = blockIdx.x * 64;
  const int k0 = blockIdx.y * 64;
  const int tid = threadIdx.x;
  {
    const int nl = tid & 63;
    const int n = n0 + nl;
#pragma unroll
    for (int p = 0; p < 16; ++p) {
      const int kl = p * 4 + (tid >> 6);
      float v = (n < N_REAL) ? w1[(size_t)(k0 + kl) * N_REAL + n] : 0.f;
      t[nl][kl] = (unsigned short)f2bf(v);
    }
  }
  __syncthreads();
  {
    const int kl = tid & 63;
#pragma unroll
    for (int p = 0; p < 16; ++p) {
      const int nl2 = p * 4 + (tid >> 6);
      const int n = n0 + nl2;
      const int slot = ((kl >> 3) ^ (n & 7)) & 7;
      w1t[(size_t)n * K_DIM + k0 + slot * 8 + (kl & 7)] = t[nl2][kl];
    }
  }
}

// ---- P2: W2T fp32 [40][1024] (transposed, padded) + b1 padded [1024]
__global__ __launch_bounds__(256)
void prep_small_kernel(const float* __restrict__ w2, const float* __restrict__ b1,
                       float* __restrict__ w2t, float* __restrict__ b1p) {
  const int i = blockIdx.x * 256 + threadIdx.x;
  if (i < 40 * NP) {
    const int j = i >> 10, k = i & (NP - 1);
    w2t[i] = (k < N_REAL) ? w2[(size_t)k * 40 + j] : 0.f;
  }
  const int t2 = i - 40 * NP;
  if (t2 >= 0 && t2 < NP)
    b1p[t2] = (t2 < N_REAL) ? b1[t2] : 0.f;
}

// =====================================================================
// G1: h1 = relu(A @ W1T^T + b1). 256x256 tile, BK=64, 4-phase schedule,
// counted vmcnt, A(t+1) staged at ph1, B(t+2) at ph3/ph4.
// SBAR pins the scheduler on BOTH sides: s_barrier is IntrNoMem in LLVM,
// so without the sched_barriers plain ds_reads can hoist/sink across it
// past other waves' drain points (the R7 cross-wave race).
// =====================================================================
#define SBAR() do { __builtin_amdgcn_sched_barrier(0); __builtin_amdgcn_s_barrier(); __builtin_amdgcn_sched_barrier(0); } while (0)
#define WAIT_LGKM0() do { asm volatile("s_waitcnt lgkmcnt(0)" ::: "memory"); __builtin_amdgcn_sched_barrier(0); } while (0)
#define VMWAIT(N) do { asm volatile("s_waitcnt vmcnt(" #N ")" ::: "memory"); __builtin_amdgcn_sched_barrier(0); } while (0)

// stage one 128-row half-tile (16 KiB): 2 x global_load_lds per thread
#define STAGE(DSTREG, GBASE, ROWBASE, HALF, TK) do {                                   \
  _Pragma("unroll")                                                                    \
  for (int _i = 0; _i < 2; ++_i) {                                                     \
    const int _ch = wid * 2 + _i;                                                      \
    const int _row = (HALF) * 128 + _ch * 8 + (lane >> 3);                             \
    __builtin_amdgcn_global_load_lds(                                                  \
      (const __attribute__((address_space(1))) void*)((GBASE) +                        \
          (size_t)((ROWBASE) + _row) * K_DIM + (TK) * 64 + (lane & 7) * 8),            \
      (__attribute__((address_space(3))) void*)((DSTREG) + (HALF) * 16384 + _ch * 1024), \
      16, 0, 0);                                                                       \
  }                                                                                    \
} while (0)

#define LDA4(AV, MIBASE, ABUF) do {                                                    \
  _Pragma("unroll")                                                                    \
  for (int _mi = 0; _mi < 4; ++_mi) {                                                  \
    _Pragma("unroll")                                                                  \
    for (int _kk = 0; _kk < 2; ++_kk) {                                                \
      const int _r = wr * 128 + ((MIBASE) + _mi) * 16 + r15;                           \
      AV[_mi][_kk] = *(const bf16x8*)((ABUF) + _r * 128 + (((_kk)*4 + hi4) ^ (_r & 7)) * 16); \
    }                                                                                  \
  }                                                                                    \
} while (0)

#define LDB2(BV, NIBASE, BBUF) do {                                                    \
  _Pragma("unroll")                                                                    \
  for (int _ni = 0; _ni < 2; ++_ni) {                                                  \
    _Pragma("unroll")                                                                  \
    for (int _kk = 0; _kk < 2; ++_kk) {                                                \
      const int _r = wc * 64 + ((NIBASE) + _ni) * 16 + r15;                            \
      BV[_ni][_kk] = *(const bf16x8*)((BBUF) + _r * 128 + (((_kk)*4 + hi4) ^ (_r & 7)) * 16); \
    }                                                                                  \
  }                                                                                    \
} while (0)

#define MFMA_Q(AV, BV, MIBASE, NIBASE) do {                                            \
  _Pragma("unroll")                                                                    \
  for (int _mi = 0; _mi < 4; ++_mi)                                                    \
    _Pragma("unroll")                                                                  \
    for (int _ni = 0; _ni < 2; ++_ni)                                                  \
      _Pragma("unroll")                                                                \
      for (int _kk = 0; _kk < 2; ++_kk)                                                \
        acc[(MIBASE) + _mi][(NIBASE) + _ni] = __builtin_amdgcn_mfma_f32_16x16x32_bf16( \
            AV[_mi][_kk], BV[_ni][_kk], acc[(MIBASE) + _mi][(NIBASE) + _ni], 0, 0, 0); \
} while (0)

// one K-tile = 4 phases. SA: stage A(t+1) (both halves, ph1). SB: stage B(t+2)
// at ph3/ph4 into the CURRENT B buffer (its reads finished at ph2-end barrier).
#define TILE_BODY(T, AB, BB, ABN, SA, SB, WAITSTMT) do {                               \
  /* ---- phase 1 ---- */                                                              \
  LDA4(av, 0, (AB));                                                                   \
  LDB2(bv0, 0, (BB));                                                                  \
  if (SA) { STAGE((ABN), a, m0, 0, (T) + 1); STAGE((ABN), a, m0, 1, (T) + 1); }        \
  SBAR();                                                                              \
  WAIT_LGKM0();                                                                        \
  __builtin_amdgcn_s_setprio(1);                                                       \
  MFMA_Q(av, bv0, 0, 0);                                                               \
  __builtin_amdgcn_s_setprio(0);                                                       \
  SBAR();                                                                              \
  /* ---- phase 2 ---- */                                                              \
  LDB2(bv1, 2, (BB));                                                                  \
  SBAR();                                                                              \
  WAIT_LGKM0();                                                                        \
  __builtin_amdgcn_s_setprio(1);                                                       \
  MFMA_Q(av, bv1, 0, 2);                                                               \
  __builtin_amdgcn_s_setprio(0);                                                       \
  SBAR();                                                                              \
  /* ---- phase 3 ---- */                                                              \
  LDA4(av, 4, (AB));                                                                   \
  if (SB) STAGE((BB), w1t, n0, 0, (T) + 2);                                            \
  SBAR();                                                                              \
  WAIT_LGKM0();                                                                        \
  __builtin_amdgcn_s_setprio(1);                                                       \
  MFMA_Q(av, bv1, 4, 2);                                                               \
  __builtin_amdgcn_s_setprio(0);                                                       \
  SBAR();                                                                              \
  /* ---- phase 4 ---- */                                                              \
  if (SB) STAGE((BB), w1t, n0, 1, (T) + 2);                                            \
  SBAR();                                                                              \
  WAIT_LGKM0();                                                                        \
  __builtin_amdgcn_s_setprio(1);                                                       \
  MFMA_Q(av, bv0, 4, 0);                                                               \
  __builtin_amdgcn_s_setprio(0);                                                       \
  WAITSTMT;                                                                            \
  SBAR();                                                                              \
} while (0)

__global__ __launch_bounds__(512, 2)
void gemm1_8ph_kernel(const unsigned short* __restrict__ a,
                      const unsigned short* __restrict__ w1t,
                      const float* __restrict__ b1p,
                      float* __restrict__ h1) {
  extern __shared__ char L[];   // 128 KiB: A0|B0|A1|B1, 32 KiB each
  char* const Ab0 = L;
  char* const Bb0 = L + 32768;
  char* const Ab1 = L + 65536;
  char* const Bb1 = L + 65536 + 32768;

  const int tid = threadIdx.x;
  const int lane = tid & 63;
  const int wid = tid >> 6;          // 0..7
  const int wr = wid >> 2;           // 0..1 (128-row band)
  const int wc = wid & 3;            // 0..3 (64-col band)
  const int r15 = lane & 15;
  const int hi4 = lane >> 4;         // 0..3

  // bijective XCD mapping: xcd = hw&7 owns m-panels [xcd*8, xcd*8+8) x 4 n-blocks
  const int hw = blockIdx.x;
  const int mb = (hw & 7) * 8 + (hw >> 5);
  const int nb = (hw >> 3) & 3;
  const int m0 = mb * 256;
  const int n0 = nb * 256;

  f32x4 acc[8][4] = {};
  bf16x8 av[4][2], bv0[2][2], bv1[2][2];

  // prologue: A(0) 4 loads, B(0) 4, B(1) 4; drain all but B(1)
  STAGE(Ab0, a, m0, 0, 0);
  STAGE(Ab0, a, m0, 1, 0);
  STAGE(Bb0, w1t, n0, 0, 0);
  STAGE(Bb0, w1t, n0, 1, 0);
  STAGE(Bb1, w1t, n0, 0, 1);
  STAGE(Bb1, w1t, n0, 1, 1);
  VMWAIT(4);
  SBAR();

  for (int kt = 0; kt < 191; ++kt) {
    const int t = 2 * kt;
    TILE_BODY(t,     Ab0, Bb0, Ab1, 1, 1, VMWAIT(4));
    TILE_BODY(t + 1, Ab1, Bb1, Ab0, 1, 1, VMWAIT(4));
  }
  // tail: tile 382 stages A(383) only, full drain; tile 383 computes only
  TILE_BODY(382, Ab0, Bb0, Ab1, 1, 0, VMWAIT(0));
  TILE_BODY(383, Ab1, Bb1, Ab0, 0, 0, (void)0);

  // epilogue: relu(acc + b1); C/D: col = lane&15, row = (lane>>4)*4 + r
#pragma unroll
  for (int mi = 0; mi < 8; ++mi) {
#pragma unroll
    for (int ni = 0; ni < 4; ++ni) {
      const int n = n0 + wc * 64 + ni * 16 + r15;
      const float bias = b1p[n];
#pragma unroll
      for (int r = 0; r < 4; ++r) {
        const int m = m0 + wr * 128 + mi * 16 + hi4 * 4 + r;
        const float v = acc[mi][ni][r] + bias;
        h1[(size_t)m * NP + n] = v > 0.f ? v : 0.f;
      }
    }
  }
}

// ---- K2: logits = sigmoid(relu(h1 @ W2 + b2) @ W3 + b3), one wave/row,
//          rows never gathered are skipped (bsearch on sorted starts)
__global__ __launch_bounds__(256)
void layer23_kernel(const float* __restrict__ h1, const float* __restrict__ w2t,
                    const float* __restrict__ b2, const float* __restrict__ w3,
                    const float* __restrict__ b3, const int* __restrict__ starts,
                    float* __restrict__ logits) {
  const int wave = (blockIdx.x * 256 + threadIdx.x) >> 6;
  const int lane = threadIdx.x & 63;
  const int s = wave & 511;
  if (s == 0 || !row_needed(starts + (wave >> 9) * 512, s)) return;
  const float* hrow = h1 + (size_t)wave * NP;
  float acc = 0.f;
  if (lane < 40) {
    const float* wrow = w2t + lane * NP;
    for (int k = 0; k < NP; k += 8) {
      float4 h0 = *(const float4*)(hrow + k);
      float4 h4 = *(const float4*)(hrow + k + 4);
      float4 w0 = *(const float4*)(wrow + k);
      float4 w4 = *(const float4*)(wrow + k + 4);
      acc += h0.x * w0.x + h0.y * w0.y + h0.z * w0.z + h0.w * w0.w;
      acc += h4.x * w4.x + h4.y * w4.y + h4.z * w4.z + h4.w * w4.w;
    }
    acc += b2[lane];
    acc = acc > 0.f ? acc : 0.f;
    acc *= w3[lane];
  }
#pragma unroll
  for (int off = 32; off > 0; off >>= 1)
    acc += __shfl_down(acc, off);
  if (lane == 0)
    logits[wave] = 1.f / (1.f + expf(-(acc + b3[0])));
}

// ---- K3: ragged gather
__global__ __launch_bounds__(256)
void gather_kernel(const int* __restrict__ starts, const float* __restrict__ logits,
                   float* __restrict__ out) {
  const int i = blockIdx.x * 256 + threadIdx.x;
  if (i >= M_DIM) return;
  const int st = starts[i];
  int idx = st;
  if (idx < 0) idx = 0;
  if (idx > S_DIM - 1) idx = S_DIM - 1;
  out[i] = (st != 0) ? logits[((i >> 9) << 9) + idx] : 0.f;
}

extern "C" void kernel_launch(void* const* d_in, const int* in_sizes, int n_in,
                              void* d_out, int out_size, void* d_ws, size_t ws_size,
                              hipStream_t stream) {
  const float* hs = (const float*)d_in[0];
  const float* W1 = (const float*)d_in[1];
  const float* b1 = (const float*)d_in[2];
  const float* W2 = (const float*)d_in[3];
  const float* b2 = (const float*)d_in[4];
  const float* W3 = (const float*)d_in[5];
  const float* b3 = (const float*)d_in[6];
  const int* starts = (const int*)d_in[7];
  float* out = (float*)d_out;
  char* ws = (char*)d_ws;

  const size_t A_BYTES   = (size_t)M_DIM * K_DIM * 2;         // 805,306,368
  const size_t W1T_BYTES = (size_t)NP * K_DIM * 2;            //  50,331,648
  const size_t H1_BYTES  = (size_t)M_DIM * NP * 4;            //  67,108,864
  const size_t W2T_BYTES = 40 * NP * 4;
  const size_t B1P_BYTES = NP * 4;

  unsigned short* a    = (unsigned short*)ws;
  unsigned short* w1t  = (unsigned short*)(ws + A_BYTES);
  float* h1            = (float*)(ws + A_BYTES + W1T_BYTES);
  float* w2t           = (float*)(ws + A_BYTES + W1T_BYTES + H1_BYTES);
  float* b1p           = (float*)(ws + A_BYTES + W1T_BYTES + H1_BYTES + W2T_BYTES);
  float* logits        = (float*)(ws + A_BYTES + W1T_BYTES + H1_BYTES + W2T_BYTES + B1P_BYTES);

  hipFuncSetAttribute((const void*)gemm1_8ph_kernel,
                      hipFuncAttributeMaxDynamicSharedMemorySize, 131072);

  conv_a_kernel<<<2048, 256, 0, stream>>>(hs, starts, a);
  prep_w1t_kernel<<<dim3(16, 384), 256, 0, stream>>>(W1, w1t);
  prep_small_kernel<<<164, 256, 0, stream>>>(W2, b1, w2t, b1p);
  gemm1_8ph_kernel<<<256, 512, 131072, stream>>>(a, w1t, b1p, h1);
  layer23_kernel<<<4096, 256, 0, stream>>>(h1, w2t, b2, W3, b3, starts, logits);
  gather_kernel<<<64, 256, 0, stream>>>(starts, logits, out);
}